// Round 6
// baseline (701.047 us; speedup 1.0000x reference)
//
#include <hip/hip_runtime.h>
#include <math.h>

#define DEV __device__ __forceinline__

constexpr int B_   = 8;
constexpr int NTOK = 25088;          // 8 * 56 * 56 rows
constexpr int WGc  = 512;            // 8 * 64 windows
constexpr int N2c  = 49;
constexpr int HDc  = 16;
constexpr int NHc  = 8;
constexpr float SCALEq = 0.25f;      // 16^-0.5

// ---------- helpers ----------
DEV float wave_sum(float v) {
#pragma unroll
  for (int m = 32; m >= 1; m >>= 1) v += __shfl_xor(v, m);
  return v;
}

// gelu tanh-approx: 0.5*x*(1+tanh(y)) == x * sigmoid(2y) exactly.
DEV float gelu_f(float x) {
  float y = 0.7978845608028654f * (x + 0.044715f * x * x * x);
  return x / (1.f + __expf(-2.f * y));
}

// windowed row (wg*49+n) -> token row in the (rolled) image. Same map for
// gather (partition) and scatter (reverse), since roll(-s) gather == roll(+s) scatter.
DEV int win_map(int row, int shift) {
  int wg = row / 49, n = row - wg * 49;
  int b = wg >> 6, win = wg & 63;
  int sh = ((win >> 3) * 7) + n / 7;
  int sw = ((win & 7) * 7) + (n % 7);
  sh += shift; if (sh >= 56) sh -= 56;
  sw += shift; if (sw >= 56) sw -= 56;
  return b * 3136 + sh * 56 + sw;
}

// ---------- patch embed: patchify + 16->128 matmul + LN + pos ----------
__global__ __launch_bounds__(128)
void patch_k(const float* __restrict__ vis, const float* __restrict__ pw,
             const float* __restrict__ pb, const float* __restrict__ g,
             const float* __restrict__ bb, const float* __restrict__ pos,
             float* __restrict__ X) {
  int row = blockIdx.x;              // b*3136 + l
  int c = threadIdx.x;               // 0..127
  int b = row / 3136, l = row - b * 3136;
  int hp = l / 56, wp = l - hp * 56;
  __shared__ float p[16];
  __shared__ float red[2];
  if (c < 16) {
    int r = c >> 2, cc = c & 3;
    p[c] = vis[(long)b * 50176 + (hp * 4 + r) * 224 + wp * 4 + cc];
  }
  __syncthreads();
  float t = pb[c];
#pragma unroll
  for (int k = 0; k < 16; ++k) t = fmaf(p[k], pw[k * 128 + c], t);
  float s = wave_sum(t);
  if ((c & 63) == 0) red[c >> 6] = s;
  __syncthreads();
  float mu = (red[0] + red[1]) * (1.f / 128.f);
  __syncthreads();
  float d = t - mu;
  float s2 = wave_sum(d * d);
  if ((c & 63) == 0) red[c >> 6] = s2;
  __syncthreads();
  float var = (red[0] + red[1]) * (1.f / 128.f);
  float o = d * rsqrtf(var + 1e-5f) * g[c] + bb[c] + pos[(long)l * 128 + c];
  X[(long)row * 128 + c] = o;
}

// ---------- LN over rows of 128: one wave per row, float2 per lane ----------
__global__ __launch_bounds__(256)
void ln_k(const float* __restrict__ Xi, float* __restrict__ Out,
          const float* __restrict__ g, const float* __restrict__ b, int do_relu) {
  int row = blockIdx.x * 4 + (threadIdx.x >> 6);
  int lane = threadIdx.x & 63;
  long base = (long)row * 128 + lane * 2;
  float2 v = *(const float2*)&Xi[base];
  float mu = wave_sum(v.x + v.y) * (1.f / 128.f);
  float dx = v.x - mu, dy = v.y - mu;
  float var = wave_sum(dx * dx + dy * dy) * (1.f / 128.f);
  float r = rsqrtf(var + 1e-5f);
  float2 gg = *(const float2*)&g[lane * 2];
  float2 bb = *(const float2*)&b[lane * 2];
  float ox = dx * r * gg.x + bb.x;
  float oy = dy * r * gg.y + bb.y;
  if (do_relu) { ox = fmaxf(ox, 0.f); oy = fmaxf(oy, 0.f); }
  *(float2*)&Out[base] = make_float2(ox, oy);
}

// ---------- unified 64x128 tiled fp32 GEMM, 4x8 microtile, reg-prefetch ----
// OUT_MODE: 0 plain write, 1 qkv-layout (+q scale),
//           2 scatter-add into X via win_map (N=128), 3 direct add (N=128).
// ACT: 0 none, 1 gelu.  GATHER_A: A row index through win_map.
template<int OUT_MODE, int ACT, int GATHER_A>
__global__ __launch_bounds__(256)
void gemm64_k(const float* __restrict__ A, const float* __restrict__ W,
              const float* __restrict__ bias, float* __restrict__ Out,
              int N, int K, int lda, int shift) {
  __shared__ float As[16][64];
  __shared__ float Bs[16][128];
  int tid = threadIdx.x;
  int m0 = blockIdx.x * 64, n0 = blockIdx.y * 128;
  int tx = tid & 15, ty = tid >> 4;
  float acc[4][8] = {};
  int ar = tid >> 2;             // 0..63 A-load row
  int ak = (tid & 3) * 4;        // 0,4,8,12
  long asrc = GATHER_A ? (long)win_map(m0 + ar, shift) * lda : (long)(m0 + ar) * lda;
  int bk = tid >> 5;             // 0..7
  int bj = (tid & 31) * 4;

  // preload k0 = 0
  float4 a0 = *(const float4*)&A[asrc + ak];
  float4 b0 = *(const float4*)&W[(long)bk * N + n0 + bj];
  float4 b1 = *(const float4*)&W[(long)(bk + 8) * N + n0 + bj];

  for (int k0 = 0; k0 < K; k0 += 16) {
    __syncthreads();
    As[ak + 0][ar] = a0.x; As[ak + 1][ar] = a0.y;
    As[ak + 2][ar] = a0.z; As[ak + 3][ar] = a0.w;
    *(float4*)&Bs[bk][bj] = b0;
    *(float4*)&Bs[bk + 8][bj] = b1;
    __syncthreads();
    if (k0 + 16 < K) {           // issue next-tile loads; hide under compute
      a0 = *(const float4*)&A[asrc + k0 + 16 + ak];
      b0 = *(const float4*)&W[(long)(k0 + 16 + bk) * N + n0 + bj];
      b1 = *(const float4*)&W[(long)(k0 + 16 + bk + 8) * N + n0 + bj];
    }
#pragma unroll
    for (int k = 0; k < 16; ++k) {
      float4 av = *(const float4*)&As[k][ty * 4];
      float4 bv0 = *(const float4*)&Bs[k][tx * 4];
      float4 bv1 = *(const float4*)&Bs[k][64 + tx * 4];
      float a4r[4] = {av.x, av.y, av.z, av.w};
      float b8[8] = {bv0.x, bv0.y, bv0.z, bv0.w, bv1.x, bv1.y, bv1.z, bv1.w};
#pragma unroll
      for (int i = 0; i < 4; ++i)
#pragma unroll
        for (int j = 0; j < 8; ++j)
          acc[i][j] = fmaf(a4r[i], b8[j], acc[i][j]);
    }
  }

#pragma unroll
  for (int i = 0; i < 4; ++i) {
    int row = m0 + ty * 4 + i;
    int dst = (OUT_MODE == 2) ? win_map(row, shift) : row;
#pragma unroll
    for (int j = 0; j < 8; ++j) {
      int col = n0 + ((j < 4) ? (tx * 4 + j) : (64 + tx * 4 + j - 4));
      float val = acc[i][j] + bias[col];
      if (ACT == 1) val = gelu_f(val);
      if (OUT_MODE == 0) {
        Out[(long)row * N + col] = val;
      } else if (OUT_MODE == 1) {    // qkv layout
        int t = col >> 7, cc = col & 127, h = cc >> 4, d = cc & 15;
        if (t == 0) val *= SCALEq;
        int wg = row / 49, n = row - wg * 49;
        Out[((((long)t * WGc + wg) * NHc + h) * N2c + n) * HDc + d] = val;
      } else {                        // 2 / 3: accumulate into residual
        Out[(long)dst * 128 + col] += val;
      }
    }
  }
}

// ---------- attention: one block per (window, head) ----------
__global__ __launch_bounds__(256)
void attn_k(const float* __restrict__ QKV, float* __restrict__ AO,
            const float* __restrict__ rpb, int shift) {
  int wg = blockIdx.x >> 3;
  int h  = blockIdx.x & 7;
  int tid = threadIdx.x;
  __shared__ float Qs[49][17], Ks[49][17], Vs[49][17];
  __shared__ float S[49][50];
  const float* Qp = QKV + (((long)0 * WGc + wg) * NHc + h) * N2c * HDc;
  const float* Kp = QKV + (((long)1 * WGc + wg) * NHc + h) * N2c * HDc;
  const float* Vp = QKV + (((long)2 * WGc + wg) * NHc + h) * N2c * HDc;
  for (int idx = tid; idx < 49 * 16; idx += 256) {
    int n = idx >> 4, d = idx & 15;
    Qs[n][d] = Qp[idx]; Ks[n][d] = Kp[idx]; Vs[n][d] = Vp[idx];
  }
  __syncthreads();
  int win = wg & 63, wy = win >> 3, wx = win & 7;
  for (int idx = tid; idx < 49 * 49; idx += 256) {
    int i = idx / 49, j = idx - i * 49;
    float s = 0.f;
#pragma unroll
    for (int d = 0; d < 16; ++d) s = fmaf(Qs[i][d], Ks[j][d], s);
    int pyi = i / 7, pxi = i - pyi * 7, pyj = j / 7, pxj = j - pyj * 7;
    int rel = (pyi - pyj + 6) * 13 + (pxi - pxj + 6);
    s += rpb[rel * 8 + h];
    if (shift) {
      int shi = wy * 7 + pyi, swi = wx * 7 + pxi;
      int shj = wy * 7 + pyj, swj = wx * 7 + pxj;
      int ri = (shi < 49 ? 0 : (shi < 53 ? 1 : 2)) * 3 + (swi < 49 ? 0 : (swi < 53 ? 1 : 2));
      int rj = (shj < 49 ? 0 : (shj < 53 ? 1 : 2)) * 3 + (swj < 49 ? 0 : (swj < 53 ? 1 : 2));
      if (ri != rj) s -= 100.f;
    }
    S[i][j] = s;
  }
  __syncthreads();
  int lane = tid & 63, wv = tid >> 6;
  for (int i = wv; i < 49; i += 4) {
    float v = lane < 49 ? S[i][lane] : -1e30f;
    float m = v;
#pragma unroll
    for (int d = 32; d >= 1; d >>= 1) m = fmaxf(m, __shfl_xor(m, d));
    float e = lane < 49 ? __expf(v - m) : 0.f;
    float s = e;
#pragma unroll
    for (int d = 32; d >= 1; d >>= 1) s += __shfl_xor(s, d);
    if (lane < 49) S[i][lane] = e / s;
  }
  __syncthreads();
  for (int idx = tid; idx < 49 * 16; idx += 256) {
    int i = idx >> 4, d = idx & 15;
    float o = 0.f;
    for (int j = 0; j < 49; ++j) o = fmaf(S[i][j], Vs[j][d], o);
    AO[((long)wg * 49 + i) * 128 + h * 16 + d] = o;
  }
}

// ---------- W1 k-group presum: W1s[a][c] = sum_{q=0..3} W1[4a+q][c] ----------
// Exact because the nearest-4x-upsampled head input repeats each Y value over
// aligned groups of 4 consecutive k (s*128 % 4 == 0 and 224 % 4 == 0).
__global__ __launch_bounds__(256)
void w1sum_k(const float* __restrict__ W1, float* __restrict__ W1s) {
  int a = blockIdx.x, c = threadIdx.x;
  float s = W1[(4 * a + 0) * 256 + c] + W1[(4 * a + 1) * 256 + c] +
            W1[(4 * a + 2) * 256 + c] + W1[(4 * a + 3) * 256 + c];
  W1s[a * 256 + c] = s;
}

// ---------- head: gather -> K=32 GEMM -> relu -> dot W2 (single LDS pass) ----------
__global__ __launch_bounds__(512)
void head_k(const float* __restrict__ Y, const float* __restrict__ W1s,
            const float* __restrict__ b1, const float* __restrict__ W2,
            const float* __restrict__ b2, float* __restrict__ Out) {
  __shared__ float As[32][128];   // [a][row]  16 KB
  __shared__ float Ws[32][256];   // [a][col]  32 KB
  int tid = threadIdx.x;
  int m0 = blockIdx.x * 128;

  {
    int arow = tid >> 2;               // 0..127
    int rg = m0 + arow;
    int b = rg / 50176;
    int r = rg - b * 50176;
    int ch = r / 392;
    int s = r - ch * 392;
    long ybase = (long)b * 401408 + (long)ch * 3136;
    int a0 = (tid & 3) * 8;
    int tb = s * 128 + a0 * 4;
#pragma unroll
    for (int e = 0; e < 8; ++e) {
      int t = tb + e * 4;              // < 50176
      int H = t / 224, Wp = t - H * 224;
      As[a0 + e][arow] = Y[ybase + (H >> 2) * 56 + (Wp >> 2)];
    }
  }
  for (int i = tid; i < 2048; i += 512) {
    int id4 = i * 4;
    *(float4*)&Ws[id4 >> 8][id4 & 255] = *(const float4*)&W1s[id4];
  }
  __syncthreads();

  int tx = tid & 31, ty = tid >> 5;    // 32 x 16
  float acc[8][8] = {};
#pragma unroll 4
  for (int k = 0; k < 32; ++k) {
    float4 a0 = *(const float4*)&As[k][ty * 8];
    float4 a1 = *(const float4*)&As[k][ty * 8 + 4];
    float a8[8] = {a0.x, a0.y, a0.z, a0.w, a1.x, a1.y, a1.z, a1.w};
    float w8[8];
#pragma unroll
    for (int cc = 0; cc < 8; ++cc) w8[cc] = Ws[k][tx + 32 * cc];
#pragma unroll
    for (int rr = 0; rr < 8; ++rr)
#pragma unroll
      for (int cc = 0; cc < 8; ++cc)
        acc[rr][cc] = fmaf(a8[rr], w8[cc], acc[rr][cc]);
  }

  float b2v = b2[0];
#pragma unroll
  for (int rr = 0; rr < 8; ++rr) {
    float p = 0.f;
#pragma unroll
    for (int cc = 0; cc < 8; ++cc) {
      int col = tx + 32 * cc;
      float hval = fmaxf(acc[rr][cc] + b1[col], 0.f);
      p = fmaf(hval, W2[col], p);
    }
#pragma unroll
    for (int d = 16; d >= 1; d >>= 1) p += __shfl_xor(p, d);
    if (tx == 0) Out[(long)m0 + ty * 8 + rr] = p + b2v;
  }
}

// ---------- launch ----------
extern "C" void kernel_launch(void* const* d_in, const int* in_sizes, int n_in,
                              void* d_out, int out_size, void* d_ws, size_t ws_size,
                              hipStream_t stream) {
  const float* visible = (const float*)d_in[1];
  const float* patch_w = (const float*)d_in[2];
  const float* patch_b = (const float*)d_in[3];
  const float* pn_g    = (const float*)d_in[4];
  const float* pn_b    = (const float*)d_in[5];
  const float* pos     = (const float*)d_in[6];
  const float* norm1_g = (const float*)d_in[7];
  const float* norm1_b = (const float*)d_in[8];
  const float* qkv_w   = (const float*)d_in[9];
  const float* qkv_b   = (const float*)d_in[10];
  const float* proj_w  = (const float*)d_in[11];
  const float* proj_b  = (const float*)d_in[12];
  const float* norm2_g = (const float*)d_in[13];
  const float* norm2_b = (const float*)d_in[14];
  const float* fc1_w   = (const float*)d_in[15];
  const float* fc1_b   = (const float*)d_in[16];
  const float* fc2_w   = (const float*)d_in[17];
  const float* fc2_b   = (const float*)d_in[18];
  const float* rpb     = (const float*)d_in[19];
  const float* normf_g = (const float*)d_in[20];
  const float* normf_b = (const float*)d_in[21];
  const float* h1w     = (const float*)d_in[22];
  const float* h1b     = (const float*)d_in[23];
  const float* h2w     = (const float*)d_in[24];
  const float* h2b     = (const float*)d_in[25];
  float* out = (float*)d_out;

  float* X   = (float*)d_ws;                    // 25088*128
  float* XN  = X  + (long)NTOK * 128;           // 25088*128 (also Y)
  float* BIG = XN + (long)NTOK * 128;           // 25088*512
  float* QKV = BIG;                             // 25088*384
  float* AO  = BIG + (long)NTOK * 384;          // 25088*128
  float* Hb  = BIG;                             // 25088*512 (reuses QKV+AO)
  float* Y   = XN;
  float* W1s = BIG;                             // 32*256, reuses BIG after MLP

  patch_k<<<NTOK, 128, 0, stream>>>(visible, patch_w, patch_b, pn_g, pn_b, pos, X);

  for (int layer = 0; layer < 2; ++layer) {
    int shift = layer ? 3 : 0;
    ln_k<<<NTOK / 4, 256, 0, stream>>>(X, XN, norm1_g + layer * 128, norm1_b + layer * 128, 0);
    gemm64_k<1, 0, 1><<<dim3(392, 3), 256, 0, stream>>>(
        XN, qkv_w + (long)layer * 128 * 384, qkv_b + layer * 384, QKV, 384, 128, 128, shift);
    attn_k<<<WGc * 8, 256, 0, stream>>>(QKV, AO, rpb + (long)layer * 169 * 8, shift);
    gemm64_k<2, 0, 0><<<dim3(392, 1), 256, 0, stream>>>(
        AO, proj_w + (long)layer * 128 * 128, proj_b + layer * 128, X, 128, 128, 128, shift);
    ln_k<<<NTOK / 4, 256, 0, stream>>>(X, XN, norm2_g + layer * 128, norm2_b + layer * 128, 0);
    gemm64_k<0, 1, 0><<<dim3(392, 4), 256, 0, stream>>>(
        XN, fc1_w + (long)layer * 128 * 512, fc1_b + layer * 512, Hb, 512, 128, 128, 0);
    gemm64_k<3, 0, 0><<<dim3(392, 1), 256, 0, stream>>>(
        Hb, fc2_w + (long)layer * 512 * 128, fc2_b + layer * 128, X, 128, 512, 512, 0);
  }

  ln_k<<<NTOK / 4, 256, 0, stream>>>(X, Y, normf_g, normf_b, 1);
  w1sum_k<<<32, 256, 0, stream>>>(h1w, W1s);
  head_k<<<3136, 512, 0, stream>>>(Y, W1s, h1b, h2w, h2b, out);
}

// Round 8
// 537.359 us; speedup vs baseline: 1.3046x; 1.3046x over previous
//
#include <hip/hip_runtime.h>
#include <math.h>

#define DEV __device__ __forceinline__

constexpr int B_   = 8;
constexpr int NTOK = 25088;          // 8 * 56 * 56 rows
constexpr int WGc  = 512;            // 8 * 64 windows
constexpr int N2c  = 49;
constexpr int HDc  = 16;
constexpr int NHc  = 8;
constexpr float SCALEq = 0.25f;      // 16^-0.5

typedef _Float16 f16x8 __attribute__((ext_vector_type(8)));
typedef float    f32x4 __attribute__((ext_vector_type(4)));

// ---------- helpers ----------
DEV float wave_sum(float v) {
#pragma unroll
  for (int m = 32; m >= 1; m >>= 1) v += __shfl_xor(v, m);
  return v;
}

// gelu tanh-approx: 0.5*x*(1+tanh(y)) == x * sigmoid(2y) exactly.
DEV float gelu_f(float x) {
  float y = 0.7978845608028654f * (x + 0.044715f * x * x * x);
  return x / (1.f + __expf(-2.f * y));
}

// windowed row (wg*49+n) -> token row in the (rolled) image. Same map for
// gather (partition) and scatter (reverse), since roll(-s) gather == roll(+s) scatter.
DEV int win_map(int row, int shift) {
  int wg = row / 49, n = row - wg * 49;
  int b = wg >> 6, win = wg & 63;
  int sh = ((win >> 3) * 7) + n / 7;
  int sw = ((win & 7) * 7) + (n % 7);
  sh += shift; if (sh >= 56) sh -= 56;
  sw += shift; if (sw >= 56) sw -= 56;
  return b * 3136 + sh * 56 + sw;
}

// split a float into hi+lo f16 pair (3-product trick recovers fp32-level GEMM)
DEV void split8(const float* __restrict__ x, ushort* hp, ushort* lp) {
  f16x8 h, l;
#pragma unroll
  for (int j = 0; j < 8; ++j) {
    float v = x[j];
    _Float16 hh = (_Float16)v;
    h[j] = hh;
    l[j] = (_Float16)(v - (float)hh);
  }
  *(f16x8*)hp = h;
  *(f16x8*)lp = l;
}

// ---------- patch embed: patchify + 16->128 matmul + LN + pos ----------
__global__ __launch_bounds__(128)
void patch_k(const float* __restrict__ vis, const float* __restrict__ pw,
             const float* __restrict__ pb, const float* __restrict__ g,
             const float* __restrict__ bb, const float* __restrict__ pos,
             float* __restrict__ X) {
  int row = blockIdx.x;              // b*3136 + l
  int c = threadIdx.x;               // 0..127
  int b = row / 3136, l = row - b * 3136;
  int hp = l / 56, wp = l - hp * 56;
  __shared__ float p[16];
  __shared__ float red[2];
  if (c < 16) {
    int r = c >> 2, cc = c & 3;
    p[c] = vis[(long)b * 50176 + (hp * 4 + r) * 224 + wp * 4 + cc];
  }
  __syncthreads();
  float t = pb[c];
#pragma unroll
  for (int k = 0; k < 16; ++k) t = fmaf(p[k], pw[k * 128 + c], t);
  float s = wave_sum(t);
  if ((c & 63) == 0) red[c >> 6] = s;
  __syncthreads();
  float mu = (red[0] + red[1]) * (1.f / 128.f);
  __syncthreads();
  float d = t - mu;
  float s2 = wave_sum(d * d);
  if ((c & 63) == 0) red[c >> 6] = s2;
  __syncthreads();
  float var = (red[0] + red[1]) * (1.f / 128.f);
  float o = d * rsqrtf(var + 1e-5f) * g[c] + bb[c] + pos[(long)l * 128 + c];
  X[(long)row * 128 + c] = o;
}

// ---------- LN over rows of 128: one wave per row, float2 per lane ----------
__global__ __launch_bounds__(256)
void ln_k(const float* __restrict__ Xi, float* __restrict__ Out,
          const float* __restrict__ g, const float* __restrict__ b, int do_relu) {
  int row = blockIdx.x * 4 + (threadIdx.x >> 6);
  int lane = threadIdx.x & 63;
  long base = (long)row * 128 + lane * 2;
  float2 v = *(const float2*)&Xi[base];
  float mu = wave_sum(v.x + v.y) * (1.f / 128.f);
  float dx = v.x - mu, dy = v.y - mu;
  float var = wave_sum(dx * dx + dy * dy) * (1.f / 128.f);
  float r = rsqrtf(var + 1e-5f);
  float2 gg = *(const float2*)&g[lane * 2];
  float2 bb = *(const float2*)&b[lane * 2];
  float ox = dx * r * gg.x + bb.x;
  float oy = dy * r * gg.y + bb.y;
  if (do_relu) { ox = fmaxf(ox, 0.f); oy = fmaxf(oy, 0.f); }
  *(float2*)&Out[base] = make_float2(ox, oy);
}

// ---------- MFMA split-f16 GEMM: BM=64, BN=128, BK=32, 4 waves (2m x 2n) ----
// Each wave: 32x64 output = 2x4 fragments of 16x16, split-f16 3-MFMA per frag.
// LDS holds A and B tiles in FRAGMENT ORDER: chunk = tile*64 + lane (16B/lane,
// lane-consecutive ds_read_b128, conflict-free).
// OUT_MODE: 0 plain write, 1 qkv-layout (+q scale),
//           2 scatter-add via win_map (N=128), 3 direct add (N=128).
// ACT: 0 none, 1 gelu.  GATHER_A: A row index through win_map.
template<int OUT_MODE, int ACT, int GATHER_A>
__global__ __launch_bounds__(256)
void mgemm_k(const float* __restrict__ A, const float* __restrict__ W,
             const float* __restrict__ bias, float* __restrict__ Out,
             int N, int K, int lda, int shift) {
  __shared__ __align__(16) ushort Ah[2048], Al[2048];   // 4KB + 4KB
  __shared__ __align__(16) ushort Bh[4096], Bl[4096];   // 8KB + 8KB
  int tid = threadIdx.x;
  int m0 = blockIdx.x * 64, n0 = blockIdx.y * 128;
  int lane = tid & 63, wid = tid >> 6;
  int wm = wid >> 1, wn = wid & 1;

  f32x4 acc[2][4];
#pragma unroll
  for (int mi = 0; mi < 2; ++mi)
#pragma unroll
    for (int ni = 0; ni < 4; ++ni) acc[mi][ni] = (f32x4){0.f, 0.f, 0.f, 0.f};

  // A staging: thread -> (row sr, k-group sk8); reads 8 contiguous k floats.
  int sr = tid >> 2;            // 0..63
  int sk8 = tid & 3;            // 0..3
  long asrc = GATHER_A ? (long)win_map(m0 + sr, shift) * lda
                       : (long)(m0 + sr) * lda;
  int achunk = ((sr >> 4) * 64 + sk8 * 16 + (sr & 15)) * 8;

  // B staging: 2 tasks/thread -> (col bn, k-group bk8); reads 8 strided k floats
  // (transpose-at-stage into fragment order; coalesced across lanes per j).
  int bn0_ = tid & 127, bk80 = tid >> 7;
  int bn1_ = bn0_, bk81 = bk80 + 2;
  int bchunk0 = ((bn0_ >> 4) * 64 + bk80 * 16 + (bn0_ & 15)) * 8;
  int bchunk1 = ((bn1_ >> 4) * 64 + bk81 * 16 + (bn1_ & 15)) * 8;

  float areg[8], breg0[8], breg1[8];
  auto loadA = [&](int k0) {
    float4 t0 = *(const float4*)&A[asrc + k0 + sk8 * 8];
    float4 t1 = *(const float4*)&A[asrc + k0 + sk8 * 8 + 4];
    areg[0] = t0.x; areg[1] = t0.y; areg[2] = t0.z; areg[3] = t0.w;
    areg[4] = t1.x; areg[5] = t1.y; areg[6] = t1.z; areg[7] = t1.w;
  };
  auto loadB = [&](int k0) {
#pragma unroll
    for (int j = 0; j < 8; ++j)
      breg0[j] = W[(long)(k0 + bk80 * 8 + j) * N + n0 + bn0_];
#pragma unroll
    for (int j = 0; j < 8; ++j)
      breg1[j] = W[(long)(k0 + bk81 * 8 + j) * N + n0 + bn1_];
  };

  loadA(0); loadB(0);
  for (int k0 = 0; k0 < K; k0 += 32) {
    __syncthreads();
    split8(areg, &Ah[achunk], &Al[achunk]);
    split8(breg0, &Bh[bchunk0], &Bl[bchunk0]);
    split8(breg1, &Bh[bchunk1], &Bl[bchunk1]);
    __syncthreads();
    if (k0 + 32 < K) { loadA(k0 + 32); loadB(k0 + 32); }

    f16x8 ah[2], al[2], bh[4], bl[4];
#pragma unroll
    for (int mi = 0; mi < 2; ++mi) {
      int c = ((wm * 2 + mi) * 64 + lane) * 8;
      ah[mi] = *(const f16x8*)&Ah[c];
      al[mi] = *(const f16x8*)&Al[c];
    }
#pragma unroll
    for (int ni = 0; ni < 4; ++ni) {
      int c = ((wn * 4 + ni) * 64 + lane) * 8;
      bh[ni] = *(const f16x8*)&Bh[c];
      bl[ni] = *(const f16x8*)&Bl[c];
    }
#pragma unroll
    for (int mi = 0; mi < 2; ++mi)
#pragma unroll
      for (int ni = 0; ni < 4; ++ni) {
        acc[mi][ni] = __builtin_amdgcn_mfma_f32_16x16x32_f16(ah[mi], bh[ni], acc[mi][ni], 0, 0, 0);
        acc[mi][ni] = __builtin_amdgcn_mfma_f32_16x16x32_f16(ah[mi], bl[ni], acc[mi][ni], 0, 0, 0);
        acc[mi][ni] = __builtin_amdgcn_mfma_f32_16x16x32_f16(al[mi], bh[ni], acc[mi][ni], 0, 0, 0);
      }
  }

  // epilogue: D col = lane&15, row = (lane>>4)*4 + reg  [m89/m91 mapping]
  int r4 = (lane >> 4) * 4, cb = lane & 15;
#pragma unroll
  for (int mi = 0; mi < 2; ++mi) {
#pragma unroll
    for (int rr = 0; rr < 4; ++rr) {
      int row = m0 + wm * 32 + mi * 16 + r4 + rr;
      int dst = (OUT_MODE == 2) ? win_map(row, shift) : row;
#pragma unroll
      for (int ni = 0; ni < 4; ++ni) {
        int col = n0 + wn * 64 + ni * 16 + cb;
        float val = acc[mi][ni][rr] + bias[col];
        if (ACT == 1) val = gelu_f(val);
        if (OUT_MODE == 0) {
          Out[(long)row * N + col] = val;
        } else if (OUT_MODE == 1) {    // qkv layout
          int t = col >> 7, cc = col & 127, h = cc >> 4, d = cc & 15;
          if (t == 0) val *= SCALEq;
          int wg = row / 49, n = row - wg * 49;
          Out[((((long)t * WGc + wg) * NHc + h) * N2c + n) * HDc + d] = val;
        } else {                        // 2 / 3: accumulate into residual
          Out[(long)dst * 128 + col] += val;
        }
      }
    }
  }
}

// ---------- attention: one block per (window, head) ----------
__global__ __launch_bounds__(256)
void attn_k(const float* __restrict__ QKV, float* __restrict__ AO,
            const float* __restrict__ rpb, int shift) {
  int wg = blockIdx.x >> 3;
  int h  = blockIdx.x & 7;
  int tid = threadIdx.x;
  __shared__ float Qs[49][17], Ks[49][17], Vs[49][17];
  __shared__ float S[49][50];
  const float* Qp = QKV + (((long)0 * WGc + wg) * NHc + h) * N2c * HDc;
  const float* Kp = QKV + (((long)1 * WGc + wg) * NHc + h) * N2c * HDc;
  const float* Vp = QKV + (((long)2 * WGc + wg) * NHc + h) * N2c * HDc;
  for (int idx = tid; idx < 49 * 16; idx += 256) {
    int n = idx >> 4, d = idx & 15;
    Qs[n][d] = Qp[idx]; Ks[n][d] = Kp[idx]; Vs[n][d] = Vp[idx];
  }
  __syncthreads();
  int win = wg & 63, wy = win >> 3, wx = win & 7;
  for (int idx = tid; idx < 49 * 49; idx += 256) {
    int i = idx / 49, j = idx - i * 49;
    float s = 0.f;
#pragma unroll
    for (int d = 0; d < 16; ++d) s = fmaf(Qs[i][d], Ks[j][d], s);
    int pyi = i / 7, pxi = i - pyi * 7, pyj = j / 7, pxj = j - pyj * 7;
    int rel = (pyi - pyj + 6) * 13 + (pxi - pxj + 6);
    s += rpb[rel * 8 + h];
    if (shift) {
      int shi = wy * 7 + pyi, swi = wx * 7 + pxi;
      int shj = wy * 7 + pyj, swj = wx * 7 + pxj;
      int ri = (shi < 49 ? 0 : (shi < 53 ? 1 : 2)) * 3 + (swi < 49 ? 0 : (swi < 53 ? 1 : 2));
      int rj = (shj < 49 ? 0 : (shj < 53 ? 1 : 2)) * 3 + (swj < 49 ? 0 : (swj < 53 ? 1 : 2));
      if (ri != rj) s -= 100.f;
    }
    S[i][j] = s;
  }
  __syncthreads();
  int lane = tid & 63, wv = tid >> 6;
  for (int i = wv; i < 49; i += 4) {
    float v = lane < 49 ? S[i][lane] : -1e30f;
    float m = v;
#pragma unroll
    for (int d = 32; d >= 1; d >>= 1) m = fmaxf(m, __shfl_xor(m, d));
    float e = lane < 49 ? __expf(v - m) : 0.f;
    float s = e;
#pragma unroll
    for (int d = 32; d >= 1; d >>= 1) s += __shfl_xor(s, d);
    if (lane < 49) S[i][lane] = e / s;
  }
  __syncthreads();
  for (int idx = tid; idx < 49 * 16; idx += 256) {
    int i = idx >> 4, d = idx & 15;
    float o = 0.f;
    for (int j = 0; j < 49; ++j) o = fmaf(S[i][j], Vs[j][d], o);
    AO[((long)wg * 49 + i) * 128 + h * 16 + d] = o;
  }
}

// ---------- W1 k-group presum: W1s[a][c] = sum_{q=0..3} W1[4a+q][c] ----------
// Exact because the nearest-4x-upsampled head input repeats each Y value over
// aligned groups of 4 consecutive k (s*128 % 4 == 0 and 224 % 4 == 0).
__global__ __launch_bounds__(256)
void w1sum_k(const float* __restrict__ W1, float* __restrict__ W1s) {
  int a = blockIdx.x, c = threadIdx.x;
  float s = W1[(4 * a + 0) * 256 + c] + W1[(4 * a + 1) * 256 + c] +
            W1[(4 * a + 2) * 256 + c] + W1[(4 * a + 3) * 256 + c];
  W1s[a * 256 + c] = s;
}

// ---------- head: gather -> K=32 GEMM -> relu -> dot W2 (single LDS pass) ----------
__global__ __launch_bounds__(512)
void head_k(const float* __restrict__ Y, const float* __restrict__ W1s,
            const float* __restrict__ b1, const float* __restrict__ W2,
            const float* __restrict__ b2, float* __restrict__ Out) {
  __shared__ float As[32][128];   // [a][row]  16 KB
  __shared__ float Ws[32][256];   // [a][col]  32 KB
  int tid = threadIdx.x;
  int m0 = blockIdx.x * 128;

  {
    int arow = tid >> 2;               // 0..127
    int rg = m0 + arow;
    int b = rg / 50176;
    int r = rg - b * 50176;
    int ch = r / 392;
    int s = r - ch * 392;
    long ybase = (long)b * 401408 + (long)ch * 3136;
    int a0 = (tid & 3) * 8;
    int tb = s * 128 + a0 * 4;
#pragma unroll
    for (int e = 0; e < 8; ++e) {
      int t = tb + e * 4;              // < 50176
      int H = t / 224, Wp = t - H * 224;
      As[a0 + e][arow] = Y[ybase + (H >> 2) * 56 + (Wp >> 2)];
    }
  }
  for (int i = tid; i < 2048; i += 512) {
    int id4 = i * 4;
    *(float4*)&Ws[id4 >> 8][id4 & 255] = *(const float4*)&W1s[id4];
  }
  __syncthreads();

  int tx = tid & 31, ty = tid >> 5;    // 32 x 16
  float acc[8][8] = {};
#pragma unroll 4
  for (int k = 0; k < 32; ++k) {
    float4 a0 = *(const float4*)&As[k][ty * 8];
    float4 a1 = *(const float4*)&As[k][ty * 8 + 4];
    float a8[8] = {a0.x, a0.y, a0.z, a0.w, a1.x, a1.y, a1.z, a1.w};
    float w8[8];
#pragma unroll
    for (int cc = 0; cc < 8; ++cc) w8[cc] = Ws[k][tx + 32 * cc];
#pragma unroll
    for (int rr = 0; rr < 8; ++rr)
#pragma unroll
      for (int cc = 0; cc < 8; ++cc)
        acc[rr][cc] = fmaf(a8[rr], w8[cc], acc[rr][cc]);
  }

  float b2v = b2[0];
#pragma unroll
  for (int rr = 0; rr < 8; ++rr) {
    float p = 0.f;
#pragma unroll
    for (int cc = 0; cc < 8; ++cc) {
      int col = tx + 32 * cc;
      float hval = fmaxf(acc[rr][cc] + b1[col], 0.f);
      p = fmaf(hval, W2[col], p);
    }
#pragma unroll
    for (int d = 16; d >= 1; d >>= 1) p += __shfl_xor(p, d);
    if (tx == 0) Out[(long)m0 + ty * 8 + rr] = p + b2v;
  }
}

// ---------- launch ----------
extern "C" void kernel_launch(void* const* d_in, const int* in_sizes, int n_in,
                              void* d_out, int out_size, void* d_ws, size_t ws_size,
                              hipStream_t stream) {
  const float* visible = (const float*)d_in[1];
  const float* patch_w = (const float*)d_in[2];
  const float* patch_b = (const float*)d_in[3];
  const float* pn_g    = (const float*)d_in[4];
  const float* pn_b    = (const float*)d_in[5];
  const float* pos     = (const float*)d_in[6];
  const float* norm1_g = (const float*)d_in[7];
  const float* norm1_b = (const float*)d_in[8];
  const float* qkv_w   = (const float*)d_in[9];
  const float* qkv_b   = (const float*)d_in[10];
  const float* proj_w  = (const float*)d_in[11];
  const float* proj_b  = (const float*)d_in[12];
  const float* norm2_g = (const float*)d_in[13];
  const float* norm2_b = (const float*)d_in[14];
  const float* fc1_w   = (const float*)d_in[15];
  const float* fc1_b   = (const float*)d_in[16];
  const float* fc2_w   = (const float*)d_in[17];
  const float* fc2_b   = (const float*)d_in[18];
  const float* rpb     = (const float*)d_in[19];
  const float* normf_g = (const float*)d_in[20];
  const float* normf_b = (const float*)d_in[21];
  const float* h1w     = (const float*)d_in[22];
  const float* h1b     = (const float*)d_in[23];
  const float* h2w     = (const float*)d_in[24];
  const float* h2b     = (const float*)d_in[25];
  float* out = (float*)d_out;

  float* X   = (float*)d_ws;                    // 25088*128
  float* XN  = X  + (long)NTOK * 128;           // 25088*128 (also Y)
  float* BIG = XN + (long)NTOK * 128;           // 25088*512
  float* QKV = BIG;                             // 25088*384
  float* AO  = BIG + (long)NTOK * 384;          // 25088*128
  float* Hb  = BIG;                             // 25088*512 (reuses QKV+AO)
  float* Y   = XN;
  float* W1s = BIG;                             // 32*256, reuses BIG after MLP

  patch_k<<<NTOK, 128, 0, stream>>>(visible, patch_w, patch_b, pn_g, pn_b, pos, X);

  for (int layer = 0; layer < 2; ++layer) {
    int shift = layer ? 3 : 0;
    ln_k<<<NTOK / 4, 256, 0, stream>>>(X, XN, norm1_g + layer * 128, norm1_b + layer * 128, 0);
    mgemm_k<1, 0, 1><<<dim3(392, 3), 256, 0, stream>>>(
        XN, qkv_w + (long)layer * 128 * 384, qkv_b + layer * 384, QKV, 384, 128, 128, shift);
    attn_k<<<WGc * 8, 256, 0, stream>>>(QKV, AO, rpb + (long)layer * 169 * 8, shift);
    mgemm_k<2, 0, 0><<<dim3(392, 1), 256, 0, stream>>>(
        AO, proj_w + (long)layer * 128 * 128, proj_b + layer * 128, X, 128, 128, 128, shift);
    ln_k<<<NTOK / 4, 256, 0, stream>>>(X, XN, norm2_g + layer * 128, norm2_b + layer * 128, 0);
    mgemm_k<0, 1, 0><<<dim3(392, 4), 256, 0, stream>>>(
        XN, fc1_w + (long)layer * 128 * 512, fc1_b + layer * 512, Hb, 512, 128, 128, 0);
    mgemm_k<3, 0, 0><<<dim3(392, 1), 256, 0, stream>>>(
        Hb, fc2_w + (long)layer * 512 * 128, fc2_b + layer * 128, X, 128, 512, 512, 0);
  }

  ln_k<<<NTOK / 4, 256, 0, stream>>>(X, Y, normf_g, normf_b, 1);
  w1sum_k<<<32, 256, 0, stream>>>(h1w, W1s);
  head_k<<<3136, 512, 0, stream>>>(Y, W1s, h1b, h2w, h2b, out);
}

// Round 9
// 485.381 us; speedup vs baseline: 1.4443x; 1.1071x over previous
//
#include <hip/hip_runtime.h>
#include <math.h>

#define DEV __device__ __forceinline__

constexpr int B_   = 8;
constexpr int NTOK = 25088;          // 8 * 56 * 56 rows
constexpr int WGc  = 512;            // 8 * 64 windows
constexpr int N2c  = 49;
constexpr int HDc  = 16;
constexpr int NHc  = 8;
constexpr float SCALEq = 0.25f;      // 16^-0.5

typedef _Float16 f16x8 __attribute__((ext_vector_type(8)));
typedef float    f32x4 __attribute__((ext_vector_type(4)));

// ---------- helpers ----------
DEV float wave_sum(float v) {
#pragma unroll
  for (int m = 32; m >= 1; m >>= 1) v += __shfl_xor(v, m);
  return v;
}

// gelu tanh-approx: 0.5*x*(1+tanh(y)) == x * sigmoid(2y) exactly.
DEV float gelu_f(float x) {
  float y = 0.7978845608028654f * (x + 0.044715f * x * x * x);
  return x / (1.f + __expf(-2.f * y));
}

// windowed row (wg*49+n) -> token row in the (rolled) image. Same map for
// gather (partition) and scatter (reverse), since roll(-s) gather == roll(+s) scatter.
DEV int win_map(int row, int shift) {
  int wg = row / 49, n = row - wg * 49;
  int b = wg >> 6, win = wg & 63;
  int sh = ((win >> 3) * 7) + n / 7;
  int sw = ((win & 7) * 7) + (n % 7);
  sh += shift; if (sh >= 56) sh -= 56;
  sw += shift; if (sw >= 56) sw -= 56;
  return b * 3136 + sh * 56 + sw;
}

// split a float into hi+lo f16 pair (3-product trick recovers fp32-level GEMM)
DEV void split8(const float* __restrict__ x, ushort* hp, ushort* lp) {
  f16x8 h, l;
#pragma unroll
  for (int j = 0; j < 8; ++j) {
    float v = x[j];
    _Float16 hh = (_Float16)v;
    h[j] = hh;
    l[j] = (_Float16)(v - (float)hh);
  }
  *(f16x8*)hp = h;
  *(f16x8*)lp = l;
}

// ---------- patch embed: patchify + 16->128 matmul + LN + pos ----------
__global__ __launch_bounds__(128)
void patch_k(const float* __restrict__ vis, const float* __restrict__ pw,
             const float* __restrict__ pb, const float* __restrict__ g,
             const float* __restrict__ bb, const float* __restrict__ pos,
             float* __restrict__ X) {
  int row = blockIdx.x;              // b*3136 + l
  int c = threadIdx.x;               // 0..127
  int b = row / 3136, l = row - b * 3136;
  int hp = l / 56, wp = l - hp * 56;
  __shared__ float p[16];
  __shared__ float red[2];
  if (c < 16) {
    int r = c >> 2, cc = c & 3;
    p[c] = vis[(long)b * 50176 + (hp * 4 + r) * 224 + wp * 4 + cc];
  }
  __syncthreads();
  float t = pb[c];
#pragma unroll
  for (int k = 0; k < 16; ++k) t = fmaf(p[k], pw[k * 128 + c], t);
  float s = wave_sum(t);
  if ((c & 63) == 0) red[c >> 6] = s;
  __syncthreads();
  float mu = (red[0] + red[1]) * (1.f / 128.f);
  __syncthreads();
  float d = t - mu;
  float s2 = wave_sum(d * d);
  if ((c & 63) == 0) red[c >> 6] = s2;
  __syncthreads();
  float var = (red[0] + red[1]) * (1.f / 128.f);
  float o = d * rsqrtf(var + 1e-5f) * g[c] + bb[c] + pos[(long)l * 128 + c];
  X[(long)row * 128 + c] = o;
}

// ---------- LN over rows of 128: one wave per row, float2 per lane ----------
__global__ __launch_bounds__(256)
void ln_k(const float* __restrict__ Xi, float* __restrict__ Out,
          const float* __restrict__ g, const float* __restrict__ b, int do_relu) {
  int row = blockIdx.x * 4 + (threadIdx.x >> 6);
  int lane = threadIdx.x & 63;
  long base = (long)row * 128 + lane * 2;
  float2 v = *(const float2*)&Xi[base];
  float mu = wave_sum(v.x + v.y) * (1.f / 128.f);
  float dx = v.x - mu, dy = v.y - mu;
  float var = wave_sum(dx * dx + dy * dy) * (1.f / 128.f);
  float r = rsqrtf(var + 1e-5f);
  float2 gg = *(const float2*)&g[lane * 2];
  float2 bb = *(const float2*)&b[lane * 2];
  float ox = dx * r * gg.x + bb.x;
  float oy = dy * r * gg.y + bb.y;
  if (do_relu) { ox = fmaxf(ox, 0.f); oy = fmaxf(oy, 0.f); }
  *(float2*)&Out[base] = make_float2(ox, oy);
}

// ---------- MFMA split-f16 GEMM: BM=64, BN=128, BK=32, 4 waves (2m x 2n) ----
// Each wave: 32x64 output = 2x4 fragments of 16x16, split-f16 3-MFMA per frag.
// LDS holds A and B tiles in FRAGMENT ORDER: chunk = tile*64 + lane (16B/lane,
// lane-consecutive ds_read_b128, conflict-free).
// OUT_MODE: 0 plain write, 1 qkv-layout (+q scale),
//           2 scatter-add via win_map (N=128), 3 direct add (N=128).
// ACT: 0 none, 1 gelu.  GATHER_A: A row index through win_map.
template<int OUT_MODE, int ACT, int GATHER_A>
__global__ __launch_bounds__(256)
void mgemm_k(const float* __restrict__ A, const float* __restrict__ W,
             const float* __restrict__ bias, float* __restrict__ Out,
             int N, int K, int lda, int shift) {
  __shared__ __align__(16) ushort Ah[2048], Al[2048];   // 4KB + 4KB
  __shared__ __align__(16) ushort Bh[4096], Bl[4096];   // 8KB + 8KB
  int tid = threadIdx.x;
  int m0 = blockIdx.x * 64, n0 = blockIdx.y * 128;
  int lane = tid & 63, wid = tid >> 6;
  int wm = wid >> 1, wn = wid & 1;

  f32x4 acc[2][4];
#pragma unroll
  for (int mi = 0; mi < 2; ++mi)
#pragma unroll
    for (int ni = 0; ni < 4; ++ni) acc[mi][ni] = (f32x4){0.f, 0.f, 0.f, 0.f};

  // A staging: thread -> (row sr, k-group sk8); reads 8 contiguous k floats.
  int sr = tid >> 2;            // 0..63
  int sk8 = tid & 3;            // 0..3
  long asrc = GATHER_A ? (long)win_map(m0 + sr, shift) * lda
                       : (long)(m0 + sr) * lda;
  int achunk = ((sr >> 4) * 64 + sk8 * 16 + (sr & 15)) * 8;

  // B staging: 2 tasks/thread -> (col bn, k-group bk8); reads 8 strided k floats
  // (transpose-at-stage into fragment order; coalesced across lanes per j).
  int bn0_ = tid & 127, bk80 = tid >> 7;
  int bn1_ = bn0_, bk81 = bk80 + 2;
  int bchunk0 = ((bn0_ >> 4) * 64 + bk80 * 16 + (bn0_ & 15)) * 8;
  int bchunk1 = ((bn1_ >> 4) * 64 + bk81 * 16 + (bn1_ & 15)) * 8;

  float areg[8], breg0[8], breg1[8];
  auto loadA = [&](int k0) {
    float4 t0 = *(const float4*)&A[asrc + k0 + sk8 * 8];
    float4 t1 = *(const float4*)&A[asrc + k0 + sk8 * 8 + 4];
    areg[0] = t0.x; areg[1] = t0.y; areg[2] = t0.z; areg[3] = t0.w;
    areg[4] = t1.x; areg[5] = t1.y; areg[6] = t1.z; areg[7] = t1.w;
  };
  auto loadB = [&](int k0) {
#pragma unroll
    for (int j = 0; j < 8; ++j)
      breg0[j] = W[(long)(k0 + bk80 * 8 + j) * N + n0 + bn0_];
#pragma unroll
    for (int j = 0; j < 8; ++j)
      breg1[j] = W[(long)(k0 + bk81 * 8 + j) * N + n0 + bn1_];
  };

  loadA(0); loadB(0);
  for (int k0 = 0; k0 < K; k0 += 32) {
    __syncthreads();
    split8(areg, &Ah[achunk], &Al[achunk]);
    split8(breg0, &Bh[bchunk0], &Bl[bchunk0]);
    split8(breg1, &Bh[bchunk1], &Bl[bchunk1]);
    __syncthreads();
    if (k0 + 32 < K) { loadA(k0 + 32); loadB(k0 + 32); }

    f16x8 ah[2], al[2], bh[4], bl[4];
#pragma unroll
    for (int mi = 0; mi < 2; ++mi) {
      int c = ((wm * 2 + mi) * 64 + lane) * 8;
      ah[mi] = *(const f16x8*)&Ah[c];
      al[mi] = *(const f16x8*)&Al[c];
    }
#pragma unroll
    for (int ni = 0; ni < 4; ++ni) {
      int c = ((wn * 4 + ni) * 64 + lane) * 8;
      bh[ni] = *(const f16x8*)&Bh[c];
      bl[ni] = *(const f16x8*)&Bl[c];
    }
#pragma unroll
    for (int mi = 0; mi < 2; ++mi)
#pragma unroll
      for (int ni = 0; ni < 4; ++ni) {
        acc[mi][ni] = __builtin_amdgcn_mfma_f32_16x16x32_f16(ah[mi], bh[ni], acc[mi][ni], 0, 0, 0);
        acc[mi][ni] = __builtin_amdgcn_mfma_f32_16x16x32_f16(ah[mi], bl[ni], acc[mi][ni], 0, 0, 0);
        acc[mi][ni] = __builtin_amdgcn_mfma_f32_16x16x32_f16(al[mi], bh[ni], acc[mi][ni], 0, 0, 0);
      }
  }

  // epilogue: D col = lane&15, row = (lane>>4)*4 + reg  [m89/m91 mapping]
  int r4 = (lane >> 4) * 4, cb = lane & 15;
#pragma unroll
  for (int mi = 0; mi < 2; ++mi) {
#pragma unroll
    for (int rr = 0; rr < 4; ++rr) {
      int row = m0 + wm * 32 + mi * 16 + r4 + rr;
      int dst = (OUT_MODE == 2) ? win_map(row, shift) : row;
#pragma unroll
      for (int ni = 0; ni < 4; ++ni) {
        int col = n0 + wn * 64 + ni * 16 + cb;
        float val = acc[mi][ni][rr] + bias[col];
        if (ACT == 1) val = gelu_f(val);
        if (OUT_MODE == 0) {
          Out[(long)row * N + col] = val;
        } else if (OUT_MODE == 1) {    // qkv layout
          int t = col >> 7, cc = col & 127, h = cc >> 4, d = cc & 15;
          if (t == 0) val *= SCALEq;
          int wg = row / 49, n = row - wg * 49;
          Out[((((long)t * WGc + wg) * NHc + h) * N2c + n) * HDc + d] = val;
        } else {                        // 2 / 3: accumulate into residual
          Out[(long)dst * 128 + col] += val;
        }
      }
    }
  }
}

// ---------- attention: one block per (window, head) ----------
__global__ __launch_bounds__(256)
void attn_k(const float* __restrict__ QKV, float* __restrict__ AO,
            const float* __restrict__ rpb, int shift) {
  int wg = blockIdx.x >> 3;
  int h  = blockIdx.x & 7;
  int tid = threadIdx.x;
  __shared__ float Qs[49][17], Ks[49][17], Vs[49][17];
  __shared__ float S[49][50];
  const float* Qp = QKV + (((long)0 * WGc + wg) * NHc + h) * N2c * HDc;
  const float* Kp = QKV + (((long)1 * WGc + wg) * NHc + h) * N2c * HDc;
  const float* Vp = QKV + (((long)2 * WGc + wg) * NHc + h) * N2c * HDc;
  for (int idx = tid; idx < 49 * 16; idx += 256) {
    int n = idx >> 4, d = idx & 15;
    Qs[n][d] = Qp[idx]; Ks[n][d] = Kp[idx]; Vs[n][d] = Vp[idx];
  }
  __syncthreads();
  int win = wg & 63, wy = win >> 3, wx = win & 7;
  for (int idx = tid; idx < 49 * 49; idx += 256) {
    int i = idx / 49, j = idx - i * 49;
    float s = 0.f;
#pragma unroll
    for (int d = 0; d < 16; ++d) s = fmaf(Qs[i][d], Ks[j][d], s);
    int pyi = i / 7, pxi = i - pyi * 7, pyj = j / 7, pxj = j - pyj * 7;
    int rel = (pyi - pyj + 6) * 13 + (pxi - pxj + 6);
    s += rpb[rel * 8 + h];
    if (shift) {
      int shi = wy * 7 + pyi, swi = wx * 7 + pxi;
      int shj = wy * 7 + pyj, swj = wx * 7 + pxj;
      int ri = (shi < 49 ? 0 : (shi < 53 ? 1 : 2)) * 3 + (swi < 49 ? 0 : (swi < 53 ? 1 : 2));
      int rj = (shj < 49 ? 0 : (shj < 53 ? 1 : 2)) * 3 + (swj < 49 ? 0 : (swj < 53 ? 1 : 2));
      if (ri != rj) s -= 100.f;
    }
    S[i][j] = s;
  }
  __syncthreads();
  int lane = tid & 63, wv = tid >> 6;
  for (int i = wv; i < 49; i += 4) {
    float v = lane < 49 ? S[i][lane] : -1e30f;
    float m = v;
#pragma unroll
    for (int d = 32; d >= 1; d >>= 1) m = fmaxf(m, __shfl_xor(m, d));
    float e = lane < 49 ? __expf(v - m) : 0.f;
    float s = e;
#pragma unroll
    for (int d = 32; d >= 1; d >>= 1) s += __shfl_xor(s, d);
    if (lane < 49) S[i][lane] = e / s;
  }
  __syncthreads();
  for (int idx = tid; idx < 49 * 16; idx += 256) {
    int i = idx >> 4, d = idx & 15;
    float o = 0.f;
    for (int j = 0; j < 49; ++j) o = fmaf(S[i][j], Vs[j][d], o);
    AO[((long)wg * 49 + i) * 128 + h * 16 + d] = o;
  }
}

// ---------- W1 k-group presum + hi/lo f16 split into FRAGMENT ORDER ----------
// W1s[a][c] = sum_{q<4} W1[4a+q][c]  (exact for the nearest-4x upsample head),
// stored as hi/lo ushorts at chunk ((c>>4)*64 + (a>>3)*16 + (c&15))*8 + (a&7).
__global__ __launch_bounds__(256)
void w1split_k(const float* __restrict__ W1, ushort* __restrict__ Bh_g,
               ushort* __restrict__ Bl_g) {
  int a = blockIdx.x, c = threadIdx.x;
  float s = W1[(4 * a + 0) * 256 + c] + W1[(4 * a + 1) * 256 + c] +
            W1[(4 * a + 2) * 256 + c] + W1[(4 * a + 3) * 256 + c];
  _Float16 h = (_Float16)s;
  _Float16 l = (_Float16)(s - (float)h);
  int idx = ((c >> 4) * 64 + (a >> 3) * 16 + (c & 15)) * 8 + (a & 7);
  Bh_g[idx] = *(const ushort*)&h;
  Bl_g[idx] = *(const ushort*)&l;
}

// ---------- head MFMA: gather -> split-f16 K=32 GEMM -> relu -> dot W2 ------
// Block: 64 rows x 256 cols, 4 waves (one 16-row m-fragment each), 16 n-frags.
__global__ __launch_bounds__(256)
void head_mfma_k(const float* __restrict__ Y, const ushort* __restrict__ Bh_g,
                 const ushort* __restrict__ Bl_g, const float* __restrict__ b1,
                 const float* __restrict__ W2, const float* __restrict__ b2,
                 float* __restrict__ Out) {
  __shared__ __align__(16) ushort Ah[2048], Al[2048];   // 64 rows x 32 k
  __shared__ __align__(16) ushort Bh[8192], Bl[8192];   // 256 cols x 32 k
  int tid = threadIdx.x;
  int m0 = blockIdx.x * 64;
  int lane = tid & 63, w = tid >> 6;

  // A gather+split: thread -> (row sr = tid>>2, k-group sk8 = tid&3)
  {
    int sr = tid >> 2, sk8 = tid & 3;
    int rg = m0 + sr;
    int b = rg / 50176;
    int r = rg - b * 50176;
    int ch = r / 392;
    int s = r - ch * 392;
    long ybase = (long)b * 401408 + (long)ch * 3136;
    float av[8];
#pragma unroll
    for (int j = 0; j < 8; ++j) {
      int t = s * 128 + (sk8 * 8 + j) * 4;       // < 50176
      int H = t / 224, Wp = t - H * 224;
      av[j] = Y[ybase + (H >> 2) * 56 + (Wp >> 2)];
    }
    int chunk = ((sr >> 4) * 64 + sk8 * 16 + (sr & 15)) * 8;
    split8(av, &Ah[chunk], &Al[chunk]);
  }
  // B copy: pre-split fragment-order hi/lo (contiguous 16B per thread-task)
  for (int i = tid; i < 1024; i += 256) {
    *(f16x8*)&Bh[i * 8] = *(const f16x8*)&Bh_g[i * 8];
    *(f16x8*)&Bl[i * 8] = *(const f16x8*)&Bl_g[i * 8];
  }
  // per-lane b1 / W2 (col = ni*16 + (lane&15))
  float b1v[16], w2v[16];
#pragma unroll
  for (int ni = 0; ni < 16; ++ni) {
    b1v[ni] = b1[ni * 16 + (lane & 15)];
    w2v[ni] = W2[ni * 16 + (lane & 15)];
  }
  __syncthreads();

  f16x8 ah = *(const f16x8*)&Ah[(w * 64 + lane) * 8];
  f16x8 al = *(const f16x8*)&Al[(w * 64 + lane) * 8];
  float p[4] = {0.f, 0.f, 0.f, 0.f};
#pragma unroll
  for (int ni = 0; ni < 16; ++ni) {
    f16x8 bh = *(const f16x8*)&Bh[(ni * 64 + lane) * 8];
    f16x8 bl = *(const f16x8*)&Bl[(ni * 64 + lane) * 8];
    f32x4 acc = (f32x4){0.f, 0.f, 0.f, 0.f};
    acc = __builtin_amdgcn_mfma_f32_16x16x32_f16(ah, bh, acc, 0, 0, 0);
    acc = __builtin_amdgcn_mfma_f32_16x16x32_f16(ah, bl, acc, 0, 0, 0);
    acc = __builtin_amdgcn_mfma_f32_16x16x32_f16(al, bh, acc, 0, 0, 0);
#pragma unroll
    for (int reg = 0; reg < 4; ++reg) {
      float hval = fmaxf(acc[reg] + b1v[ni], 0.f);
      p[reg] = fmaf(hval, w2v[ni], p[reg]);
    }
  }
  float b2v = b2[0];
#pragma unroll
  for (int reg = 0; reg < 4; ++reg) {
#pragma unroll
    for (int d = 1; d < 16; d <<= 1) p[reg] += __shfl_xor(p[reg], d);
    if ((lane & 15) == 0)
      Out[m0 + w * 16 + (lane >> 4) * 4 + reg] = p[reg] + b2v;
  }
}

// ---------- launch ----------
extern "C" void kernel_launch(void* const* d_in, const int* in_sizes, int n_in,
                              void* d_out, int out_size, void* d_ws, size_t ws_size,
                              hipStream_t stream) {
  const float* visible = (const float*)d_in[1];
  const float* patch_w = (const float*)d_in[2];
  const float* patch_b = (const float*)d_in[3];
  const float* pn_g    = (const float*)d_in[4];
  const float* pn_b    = (const float*)d_in[5];
  const float* pos     = (const float*)d_in[6];
  const float* norm1_g = (const float*)d_in[7];
  const float* norm1_b = (const float*)d_in[8];
  const float* qkv_w   = (const float*)d_in[9];
  const float* qkv_b   = (const float*)d_in[10];
  const float* proj_w  = (const float*)d_in[11];
  const float* proj_b  = (const float*)d_in[12];
  const float* norm2_g = (const float*)d_in[13];
  const float* norm2_b = (const float*)d_in[14];
  const float* fc1_w   = (const float*)d_in[15];
  const float* fc1_b   = (const float*)d_in[16];
  const float* fc2_w   = (const float*)d_in[17];
  const float* fc2_b   = (const float*)d_in[18];
  const float* rpb     = (const float*)d_in[19];
  const float* normf_g = (const float*)d_in[20];
  const float* normf_b = (const float*)d_in[21];
  const float* h1w     = (const float*)d_in[22];
  const float* h1b     = (const float*)d_in[23];
  const float* h2w     = (const float*)d_in[24];
  const float* h2b     = (const float*)d_in[25];
  float* out = (float*)d_out;

  float* X   = (float*)d_ws;                    // 25088*128
  float* XN  = X  + (long)NTOK * 128;           // 25088*128 (also Y)
  float* BIG = XN + (long)NTOK * 128;           // 25088*512
  float* QKV = BIG;                             // 25088*384
  float* AO  = BIG + (long)NTOK * 384;          // 25088*128
  float* Hb  = BIG;                             // 25088*512 (reuses QKV+AO)
  float* Y   = XN;
  ushort* BHG = (ushort*)BIG;                   // 8192 ushorts (frag-order W1s hi)
  ushort* BLG = BHG + 8192;                     // 8192 ushorts (lo)

  patch_k<<<NTOK, 128, 0, stream>>>(visible, patch_w, patch_b, pn_g, pn_b, pos, X);

  for (int layer = 0; layer < 2; ++layer) {
    int shift = layer ? 3 : 0;
    ln_k<<<NTOK / 4, 256, 0, stream>>>(X, XN, norm1_g + layer * 128, norm1_b + layer * 128, 0);
    mgemm_k<1, 0, 1><<<dim3(392, 3), 256, 0, stream>>>(
        XN, qkv_w + (long)layer * 128 * 384, qkv_b + layer * 384, QKV, 384, 128, 128, shift);
    attn_k<<<WGc * 8, 256, 0, stream>>>(QKV, AO, rpb + (long)layer * 169 * 8, shift);
    mgemm_k<2, 0, 0><<<dim3(392, 1), 256, 0, stream>>>(
        AO, proj_w + (long)layer * 128 * 128, proj_b + layer * 128, X, 128, 128, 128, shift);
    ln_k<<<NTOK / 4, 256, 0, stream>>>(X, XN, norm2_g + layer * 128, norm2_b + layer * 128, 0);
    mgemm_k<0, 1, 0><<<dim3(392, 4), 256, 0, stream>>>(
        XN, fc1_w + (long)layer * 128 * 512, fc1_b + layer * 512, Hb, 512, 128, 128, 0);
    mgemm_k<3, 0, 0><<<dim3(392, 1), 256, 0, stream>>>(
        Hb, fc2_w + (long)layer * 512 * 128, fc2_b + layer * 128, X, 128, 512, 512, 0);
  }

  ln_k<<<NTOK / 4, 256, 0, stream>>>(X, Y, normf_g, normf_b, 1);
  w1split_k<<<32, 256, 0, stream>>>(h1w, BHG, BLG);
  head_mfma_k<<<6272, 256, 0, stream>>>(Y, BHG, BLG, h1b, h2w, h2b, out);
}

// Round 11
// 462.740 us; speedup vs baseline: 1.5150x; 1.0489x over previous
//
#include <hip/hip_runtime.h>
#include <math.h>

#define DEV __device__ __forceinline__

constexpr int B_   = 8;
constexpr int NTOK = 25088;          // 8 * 56 * 56 rows
constexpr int WGc  = 512;            // 8 * 64 windows
constexpr int N2c  = 49;
constexpr int HDc  = 16;
constexpr int NHc  = 8;
constexpr float SCALEq = 0.25f;      // 16^-0.5

typedef _Float16 f16x8 __attribute__((ext_vector_type(8)));
typedef float    f32x4 __attribute__((ext_vector_type(4)));

// ---------- helpers ----------
DEV float wave_sum(float v) {
#pragma unroll
  for (int m = 32; m >= 1; m >>= 1) v += __shfl_xor(v, m);
  return v;
}

// gelu tanh-approx: 0.5*x*(1+tanh(y)) == x * sigmoid(2y) exactly.
DEV float gelu_f(float x) {
  float y = 0.7978845608028654f * (x + 0.044715f * x * x * x);
  return x / (1.f + __expf(-2.f * y));
}

// windowed row (wg*49+n) -> token row in the (rolled) image. Same map for
// gather (partition) and scatter (reverse), since roll(-s) gather == roll(+s) scatter.
DEV int win_map(int row, int shift) {
  int wg = row / 49, n = row - wg * 49;
  int b = wg >> 6, win = wg & 63;
  int sh = ((win >> 3) * 7) + n / 7;
  int sw = ((win & 7) * 7) + (n % 7);
  sh += shift; if (sh >= 56) sh -= 56;
  sw += shift; if (sw >= 56) sw -= 56;
  return b * 3136 + sh * 56 + sw;
}

// split a float into hi+lo f16 pair (3-product trick recovers fp32-level GEMM)
DEV void split8(const float* __restrict__ x, ushort* hp, ushort* lp) {
  f16x8 h, l;
#pragma unroll
  for (int j = 0; j < 8; ++j) {
    float v = x[j];
    _Float16 hh = (_Float16)v;
    h[j] = hh;
    l[j] = (_Float16)(v - (float)hh);
  }
  *(f16x8*)hp = h;
  *(f16x8*)lp = l;
}

// ---------- patch embed: patchify + 16->128 matmul + LN + pos ----------
__global__ __launch_bounds__(128)
void patch_k(const float* __restrict__ vis, const float* __restrict__ pw,
             const float* __restrict__ pb, const float* __restrict__ g,
             const float* __restrict__ bb, const float* __restrict__ pos,
             float* __restrict__ X) {
  int row = blockIdx.x;              // b*3136 + l
  int c = threadIdx.x;               // 0..127
  int b = row / 3136, l = row - b * 3136;
  int hp = l / 56, wp = l - hp * 56;
  __shared__ float p[16];
  __shared__ float red[2];
  if (c < 16) {
    int r = c >> 2, cc = c & 3;
    p[c] = vis[(long)b * 50176 + (hp * 4 + r) * 224 + wp * 4 + cc];
  }
  __syncthreads();
  float t = pb[c];
#pragma unroll
  for (int k = 0; k < 16; ++k) t = fmaf(p[k], pw[k * 128 + c], t);
  float s = wave_sum(t);
  if ((c & 63) == 0) red[c >> 6] = s;
  __syncthreads();
  float mu = (red[0] + red[1]) * (1.f / 128.f);
  __syncthreads();
  float d = t - mu;
  float s2 = wave_sum(d * d);
  if ((c & 63) == 0) red[c >> 6] = s2;
  __syncthreads();
  float var = (red[0] + red[1]) * (1.f / 128.f);
  float o = d * rsqrtf(var + 1e-5f) * g[c] + bb[c] + pos[(long)l * 128 + c];
  X[(long)row * 128 + c] = o;
}

// ---------- LN over rows of 128: one wave per row, float2 per lane ----------
__global__ __launch_bounds__(256)
void ln_k(const float* __restrict__ Xi, float* __restrict__ Out,
          const float* __restrict__ g, const float* __restrict__ b, int do_relu) {
  int row = blockIdx.x * 4 + (threadIdx.x >> 6);
  int lane = threadIdx.x & 63;
  long base = (long)row * 128 + lane * 2;
  float2 v = *(const float2*)&Xi[base];
  float mu = wave_sum(v.x + v.y) * (1.f / 128.f);
  float dx = v.x - mu, dy = v.y - mu;
  float var = wave_sum(dx * dx + dy * dy) * (1.f / 128.f);
  float r = rsqrtf(var + 1e-5f);
  float2 gg = *(const float2*)&g[lane * 2];
  float2 bb = *(const float2*)&b[lane * 2];
  float ox = dx * r * gg.x + bb.x;
  float oy = dy * r * gg.y + bb.y;
  if (do_relu) { ox = fmaxf(ox, 0.f); oy = fmaxf(oy, 0.f); }
  *(float2*)&Out[base] = make_float2(ox, oy);
}

// ---------- MFMA split-f16 GEMM: BM=64, BN=128, BK=32, 4 waves (2m x 2n) ----
// OUT_MODE: 0 plain write, 1 qkv-layout (+q scale),
//           2 scatter-add via win_map (N=128), 3 direct add (N=128).
// ACT: 0 none, 1 gelu.  GATHER_A: A row index through win_map.
template<int OUT_MODE, int ACT, int GATHER_A>
__global__ __launch_bounds__(256)
void mgemm_k(const float* __restrict__ A, const float* __restrict__ W,
             const float* __restrict__ bias, float* __restrict__ Out,
             int N, int K, int lda, int shift) {
  __shared__ __align__(16) ushort Ah[2048], Al[2048];   // 4KB + 4KB
  __shared__ __align__(16) ushort Bh[4096], Bl[4096];   // 8KB + 8KB
  int tid = threadIdx.x;
  int m0 = blockIdx.x * 64, n0 = blockIdx.y * 128;
  int lane = tid & 63, wid = tid >> 6;
  int wm = wid >> 1, wn = wid & 1;

  f32x4 acc[2][4];
#pragma unroll
  for (int mi = 0; mi < 2; ++mi)
#pragma unroll
    for (int ni = 0; ni < 4; ++ni) acc[mi][ni] = (f32x4){0.f, 0.f, 0.f, 0.f};

  int sr = tid >> 2;            // 0..63
  int sk8 = tid & 3;            // 0..3
  long asrc = GATHER_A ? (long)win_map(m0 + sr, shift) * lda
                       : (long)(m0 + sr) * lda;
  int achunk = ((sr >> 4) * 64 + sk8 * 16 + (sr & 15)) * 8;

  int bn0_ = tid & 127, bk80 = tid >> 7;
  int bn1_ = bn0_, bk81 = bk80 + 2;
  int bchunk0 = ((bn0_ >> 4) * 64 + bk80 * 16 + (bn0_ & 15)) * 8;
  int bchunk1 = ((bn1_ >> 4) * 64 + bk81 * 16 + (bn1_ & 15)) * 8;

  float areg[8], breg0[8], breg1[8];
  auto loadA = [&](int k0) {
    float4 t0 = *(const float4*)&A[asrc + k0 + sk8 * 8];
    float4 t1 = *(const float4*)&A[asrc + k0 + sk8 * 8 + 4];
    areg[0] = t0.x; areg[1] = t0.y; areg[2] = t0.z; areg[3] = t0.w;
    areg[4] = t1.x; areg[5] = t1.y; areg[6] = t1.z; areg[7] = t1.w;
  };
  auto loadB = [&](int k0) {
#pragma unroll
    for (int j = 0; j < 8; ++j)
      breg0[j] = W[(long)(k0 + bk80 * 8 + j) * N + n0 + bn0_];
#pragma unroll
    for (int j = 0; j < 8; ++j)
      breg1[j] = W[(long)(k0 + bk81 * 8 + j) * N + n0 + bn1_];
  };

  loadA(0); loadB(0);
  for (int k0 = 0; k0 < K; k0 += 32) {
    __syncthreads();
    split8(areg, &Ah[achunk], &Al[achunk]);
    split8(breg0, &Bh[bchunk0], &Bl[bchunk0]);
    split8(breg1, &Bh[bchunk1], &Bl[bchunk1]);
    __syncthreads();
    if (k0 + 32 < K) { loadA(k0 + 32); loadB(k0 + 32); }

    f16x8 ah[2], al[2], bh[4], bl[4];
#pragma unroll
    for (int mi = 0; mi < 2; ++mi) {
      int c = ((wm * 2 + mi) * 64 + lane) * 8;
      ah[mi] = *(const f16x8*)&Ah[c];
      al[mi] = *(const f16x8*)&Al[c];
    }
#pragma unroll
    for (int ni = 0; ni < 4; ++ni) {
      int c = ((wn * 4 + ni) * 64 + lane) * 8;
      bh[ni] = *(const f16x8*)&Bh[c];
      bl[ni] = *(const f16x8*)&Bl[c];
    }
#pragma unroll
    for (int mi = 0; mi < 2; ++mi)
#pragma unroll
      for (int ni = 0; ni < 4; ++ni) {
        acc[mi][ni] = __builtin_amdgcn_mfma_f32_16x16x32_f16(ah[mi], bh[ni], acc[mi][ni], 0, 0, 0);
        acc[mi][ni] = __builtin_amdgcn_mfma_f32_16x16x32_f16(ah[mi], bl[ni], acc[mi][ni], 0, 0, 0);
        acc[mi][ni] = __builtin_amdgcn_mfma_f32_16x16x32_f16(al[mi], bh[ni], acc[mi][ni], 0, 0, 0);
      }
  }

  int r4 = (lane >> 4) * 4, cb = lane & 15;
#pragma unroll
  for (int mi = 0; mi < 2; ++mi) {
#pragma unroll
    for (int rr = 0; rr < 4; ++rr) {
      int row = m0 + wm * 32 + mi * 16 + r4 + rr;
      int dst = (OUT_MODE == 2) ? win_map(row, shift) : row;
#pragma unroll
      for (int ni = 0; ni < 4; ++ni) {
        int col = n0 + wn * 64 + ni * 16 + cb;
        float val = acc[mi][ni][rr] + bias[col];
        if (ACT == 1) val = gelu_f(val);
        if (OUT_MODE == 0) {
          Out[(long)row * N + col] = val;
        } else if (OUT_MODE == 1) {    // qkv layout
          int t = col >> 7, cc = col & 127, h = cc >> 4, d = cc & 15;
          if (t == 0) val *= SCALEq;
          int wg = row / 49, n = row - wg * 49;
          Out[((((long)t * WGc + wg) * NHc + h) * N2c + n) * HDc + d] = val;
        } else {                        // 2 / 3: accumulate into residual
          Out[(long)dst * 128 + col] += val;
        }
      }
    }
  }
}

// ---------- rel-pos bias table: tbl[h][i][j] = rpb[REL(i,j)][h] ----------
__global__ __launch_bounds__(256)
void bias_k(const float* __restrict__ rpb, float* __restrict__ tbl) {
  int idx = blockIdx.x * 256 + threadIdx.x;   // h*2401 + i*49 + j
  if (idx >= 8 * 2401) return;
  int h = idx / 2401, r = idx - h * 2401;
  int i = r / 49, j = r - i * 49;
  int pyi = i / 7, pxi = i - pyi * 7, pyj = j / 7, pxj = j - pyj * 7;
  int rel = (pyi - pyj + 6) * 13 + (pxi - pxj + 6);
  tbl[idx] = rpb[rel * 8 + h];
}

// ---------- MFMA window attention: 1 block/window, 4 waves x 2 heads -------
// QK^T: 16x mfma 16x16x32 (d=16 zero-padded to 32), frags loaded direct from
// global. Softmax in-register on acc layout (16-lane shfl row reduce).
// P -> swizzled f16 LDS -> PV: 8 mfma (4 M-tiles x 2 K-steps).
__global__ __launch_bounds__(256)
void attn_mfma_k(const float* __restrict__ QKV, float* __restrict__ AO,
                 const float* __restrict__ btbl, int shift) {
  __shared__ __align__(16) _Float16 Pl[4][64][64];   // 32 KB
  int tid = threadIdx.x;
  int wg = blockIdx.x;
  int lane = tid & 63, w = tid >> 6;
  int li = lane & 15, lk = lane >> 4;
  int win = wg & 63, wy = win >> 3, wx = win & 7;

  // shift-mask regions (head-independent)
  int ri[4][4], rj[4];
  if (shift) {
#pragma unroll
    for (int mi = 0; mi < 4; ++mi)
#pragma unroll
      for (int reg = 0; reg < 4; ++reg) {
        int i = mi * 16 + lk * 4 + reg;
        int py = i / 7, px = i - py * 7;
        int sh = wy * 7 + py, sw = wx * 7 + px;
        ri[mi][reg] = (sh < 49 ? 0 : (sh < 53 ? 1 : 2)) * 3 + (sw < 49 ? 0 : (sw < 53 ? 1 : 2));
      }
#pragma unroll
    for (int nj = 0; nj < 4; ++nj) {
      int j = nj * 16 + li;
      int py = j / 7, px = j - py * 7;
      int sh = wy * 7 + py, sw = wx * 7 + px;
      rj[nj] = (sh < 49 ? 0 : (sh < 53 ? 1 : 2)) * 3 + (sw < 49 ? 0 : (sw < 53 ? 1 : 2));
    }
  }

  for (int hh = 0; hh < 2; ++hh) {
    int h = w * 2 + hh;
    const float* Qp = QKV + (((long)0 * WGc + wg) * NHc + h) * 784;
    const float* Kp = QKV + (((long)1 * WGc + wg) * NHc + h) * 784;
    const float* Vp = QKV + (((long)2 * WGc + wg) * NHc + h) * 784;

    // Q/K fragments: lane holds row/col = t*16+li, 8 d's at lk*8 (zero if >=16)
    f16x8 qf[4], kf[4];
#pragma unroll
    for (int t = 0; t < 4; ++t) {
      f16x8 q, k;
#pragma unroll
      for (int e = 0; e < 8; ++e) { q[e] = (_Float16)0.f; k[e] = (_Float16)0.f; }
      int r = t * 16 + li;
      if (lk < 2 && r < 49) {
        const float* pq = &Qp[r * 16 + lk * 8];
        const float* pk = &Kp[r * 16 + lk * 8];
#pragma unroll
        for (int e = 0; e < 8; ++e) {
          q[e] = (_Float16)pq[e];
          k[e] = (_Float16)pk[e];
        }
      }
      qf[t] = q; kf[t] = k;
    }

    // S = Q K^T
    f32x4 s[4][4];
#pragma unroll
    for (int mi = 0; mi < 4; ++mi)
#pragma unroll
      for (int nj = 0; nj < 4; ++nj) {
        f32x4 z = (f32x4){0.f, 0.f, 0.f, 0.f};
        s[mi][nj] = __builtin_amdgcn_mfma_f32_16x16x32_f16(qf[mi], kf[nj], z, 0, 0, 0);
      }

    // softmax rows (row i held across the 16-lane li-group)
    const float* bth = btbl + (long)h * 2401;
    char* pbase = (char*)&Pl[w][0][0];
#pragma unroll
    for (int mi = 0; mi < 4; ++mi) {
#pragma unroll
      for (int reg = 0; reg < 4; ++reg) {
        int i = mi * 16 + lk * 4 + reg;
        float sv[4];
#pragma unroll
        for (int nj = 0; nj < 4; ++nj) {
          int j = nj * 16 + li;
          float v = -1e30f;
          if (i < 49 && j < 49) {
            v = s[mi][nj][reg] + bth[i * 49 + j];
            if (shift && ri[mi][reg] != rj[nj]) v -= 100.f;
          }
          sv[nj] = v;
        }
        float m = fmaxf(fmaxf(sv[0], sv[1]), fmaxf(sv[2], sv[3]));
#pragma unroll
        for (int d = 1; d < 16; d <<= 1) m = fmaxf(m, __shfl_xor(m, d));
        float e0 = __expf(sv[0] - m), e1 = __expf(sv[1] - m);
        float e2 = __expf(sv[2] - m), e3 = __expf(sv[3] - m);
        float sum = e0 + e1 + e2 + e3;
#pragma unroll
        for (int d = 1; d < 16; d <<= 1) sum += __shfl_xor(sum, d);
        float inv = 1.f / sum;
        int rL = i;                    // row-local == i (block covers 64 rows)
        int sw4 = (rL & 7) << 4;       // XOR swizzle: 16B chunks within row
        float ee[4] = {e0, e1, e2, e3};
#pragma unroll
        for (int nj = 0; nj < 4; ++nj) {
          int byte = rL * 128 + (((nj * 16 + li) * 2) ^ sw4);
          *(_Float16*)(pbase + byte) = (_Float16)(ee[nj] * inv);
        }
      }
    }
    __syncthreads();

    // V fragments: lane holds col d=li, 8 j's at ks*32+lk*8
    f16x8 vf[2];
#pragma unroll
    for (int ks = 0; ks < 2; ++ks) {
      f16x8 v;
#pragma unroll
      for (int e = 0; e < 8; ++e) {
        int j = ks * 32 + lk * 8 + e;
        v[e] = (j < 49) ? (_Float16)Vp[j * 16 + li] : (_Float16)0.f;
      }
      vf[ks] = v;
    }

    // O = P V
    f32x4 o[4];
#pragma unroll
    for (int mi = 0; mi < 4; ++mi) {
      f32x4 acc = (f32x4){0.f, 0.f, 0.f, 0.f};
#pragma unroll
      for (int ks = 0; ks < 2; ++ks) {
        int row = mi * 16 + li;
        int byte = row * 128 + (((ks * 32 + lk * 8) * 2) ^ ((row & 7) << 4));
        f16x8 pf = *(const f16x8*)(pbase + byte);
        acc = __builtin_amdgcn_mfma_f32_16x16x32_f16(pf, vf[ks], acc, 0, 0, 0);
      }
      o[mi] = acc;
    }
#pragma unroll
    for (int mi = 0; mi < 4; ++mi) {
#pragma unroll
      for (int reg = 0; reg < 4; ++reg) {
        int i = mi * 16 + lk * 4 + reg;
        if (i < 49)
          AO[((long)wg * 49 + i) * 128 + h * 16 + li] = o[mi][reg];
      }
    }
    __syncthreads();
  }
}

// ---------- W1 k-group presum + hi/lo f16 split into FRAGMENT ORDER ----------
__global__ __launch_bounds__(256)
void w1split_k(const float* __restrict__ W1, ushort* __restrict__ Bh_g,
               ushort* __restrict__ Bl_g) {
  int a = blockIdx.x, c = threadIdx.x;
  float s = W1[(4 * a + 0) * 256 + c] + W1[(4 * a + 1) * 256 + c] +
            W1[(4 * a + 2) * 256 + c] + W1[(4 * a + 3) * 256 + c];
  _Float16 h = (_Float16)s;
  _Float16 l = (_Float16)(s - (float)h);
  int idx = ((c >> 4) * 64 + (a >> 3) * 16 + (c & 15)) * 8 + (a & 7);
  Bh_g[idx] = *(const ushort*)&h;
  Bl_g[idx] = *(const ushort*)&l;
}

// ---------- head MFMA: gather -> split-f16 K=32 GEMM -> relu -> dot W2 ------
__global__ __launch_bounds__(256)
void head_mfma_k(const float* __restrict__ Y, const ushort* __restrict__ Bh_g,
                 const ushort* __restrict__ Bl_g, const float* __restrict__ b1,
                 const float* __restrict__ W2, const float* __restrict__ b2,
                 float* __restrict__ Out) {
  __shared__ __align__(16) ushort Ah[2048], Al[2048];   // 64 rows x 32 k
  __shared__ __align__(16) ushort Bh[8192], Bl[8192];   // 256 cols x 32 k
  int tid = threadIdx.x;
  int m0 = blockIdx.x * 64;
  int lane = tid & 63, w = tid >> 6;

  {
    int sr = tid >> 2, sk8 = tid & 3;
    int rg = m0 + sr;
    int b = rg / 50176;
    int r = rg - b * 50176;
    int ch = r / 392;
    int s = r - ch * 392;
    long ybase = (long)b * 401408 + (long)ch * 3136;
    float av[8];
#pragma unroll
    for (int j = 0; j < 8; ++j) {
      int t = s * 128 + (sk8 * 8 + j) * 4;       // < 50176
      int H = t / 224, Wp = t - H * 224;
      av[j] = Y[ybase + (H >> 2) * 56 + (Wp >> 2)];
    }
    int chunk = ((sr >> 4) * 64 + sk8 * 16 + (sr & 15)) * 8;
    split8(av, &Ah[chunk], &Al[chunk]);
  }
  for (int i = tid; i < 1024; i += 256) {
    *(f16x8*)&Bh[i * 8] = *(const f16x8*)&Bh_g[i * 8];
    *(f16x8*)&Bl[i * 8] = *(const f16x8*)&Bl_g[i * 8];
  }
  float b1v[16], w2v[16];
#pragma unroll
  for (int ni = 0; ni < 16; ++ni) {
    b1v[ni] = b1[ni * 16 + (lane & 15)];
    w2v[ni] = W2[ni * 16 + (lane & 15)];
  }
  __syncthreads();

  f16x8 ah = *(const f16x8*)&Ah[(w * 64 + lane) * 8];
  f16x8 al = *(const f16x8*)&Al[(w * 64 + lane) * 8];
  float p[4] = {0.f, 0.f, 0.f, 0.f};
#pragma unroll
  for (int ni = 0; ni < 16; ++ni) {
    f16x8 bh = *(const f16x8*)&Bh[(ni * 64 + lane) * 8];
    f16x8 bl = *(const f16x8*)&Bl[(ni * 64 + lane) * 8];
    f32x4 acc = (f32x4){0.f, 0.f, 0.f, 0.f};
    acc = __builtin_amdgcn_mfma_f32_16x16x32_f16(ah, bh, acc, 0, 0, 0);
    acc = __builtin_amdgcn_mfma_f32_16x16x32_f16(ah, bl, acc, 0, 0, 0);
    acc = __builtin_amdgcn_mfma_f32_16x16x32_f16(al, bh, acc, 0, 0, 0);
#pragma unroll
    for (int reg = 0; reg < 4; ++reg) {
      float hval = fmaxf(acc[reg] + b1v[ni], 0.f);
      p[reg] = fmaf(hval, w2v[ni], p[reg]);
    }
  }
  float b2v = b2[0];
#pragma unroll
  for (int reg = 0; reg < 4; ++reg) {
#pragma unroll
    for (int d = 1; d < 16; d <<= 1) p[reg] += __shfl_xor(p[reg], d);
    if ((lane & 15) == 0)
      Out[m0 + w * 16 + (lane >> 4) * 4 + reg] = p[reg] + b2v;
  }
}

// ---------- launch ----------
extern "C" void kernel_launch(void* const* d_in, const int* in_sizes, int n_in,
                              void* d_out, int out_size, void* d_ws, size_t ws_size,
                              hipStream_t stream) {
  const float* visible = (const float*)d_in[1];
  const float* patch_w = (const float*)d_in[2];
  const float* patch_b = (const float*)d_in[3];
  const float* pn_g    = (const float*)d_in[4];
  const float* pn_b    = (const float*)d_in[5];
  const float* pos     = (const float*)d_in[6];
  const float* norm1_g = (const float*)d_in[7];
  const float* norm1_b = (const float*)d_in[8];
  const float* qkv_w   = (const float*)d_in[9];
  const float* qkv_b   = (const float*)d_in[10];
  const float* proj_w  = (const float*)d_in[11];
  const float* proj_b  = (const float*)d_in[12];
  const float* norm2_g = (const float*)d_in[13];
  const float* norm2_b = (const float*)d_in[14];
  const float* fc1_w   = (const float*)d_in[15];
  const float* fc1_b   = (const float*)d_in[16];
  const float* fc2_w   = (const float*)d_in[17];
  const float* fc2_b   = (const float*)d_in[18];
  const float* rpb     = (const float*)d_in[19];
  const float* normf_g = (const float*)d_in[20];
  const float* normf_b = (const float*)d_in[21];
  const float* h1w     = (const float*)d_in[22];
  const float* h1b     = (const float*)d_in[23];
  const float* h2w     = (const float*)d_in[24];
  const float* h2b     = (const float*)d_in[25];
  float* out = (float*)d_out;

  float* X   = (float*)d_ws;                    // 25088*128
  float* XN  = X  + (long)NTOK * 128;           // 25088*128 (also Y / bias tbl)
  float* BIG = XN + (long)NTOK * 128;           // 25088*512
  float* QKV = BIG;                             // 25088*384
  float* AO  = BIG + (long)NTOK * 384;          // 25088*128
  float* Hb  = BIG;                             // 25088*512 (reuses QKV+AO)
  float* Y   = XN;
  float* BT  = XN;                              // 8*49*49 bias table (free slot)
  ushort* BHG = (ushort*)BIG;                   // 8192 ushorts (frag-order W1s hi)
  ushort* BLG = BHG + 8192;                     // 8192 ushorts (lo)

  patch_k<<<NTOK, 128, 0, stream>>>(visible, patch_w, patch_b, pn_g, pn_b, pos, X);

  for (int layer = 0; layer < 2; ++layer) {
    int shift = layer ? 3 : 0;
    ln_k<<<NTOK / 4, 256, 0, stream>>>(X, XN, norm1_g + layer * 128, norm1_b + layer * 128, 0);
    mgemm_k<1, 0, 1><<<dim3(392, 3), 256, 0, stream>>>(
        XN, qkv_w + (long)layer * 128 * 384, qkv_b + layer * 384, QKV, 384, 128, 128, shift);
    bias_k<<<76, 256, 0, stream>>>(rpb + (long)layer * 169 * 8, BT);
    attn_mfma_k<<<WGc, 256, 0, stream>>>(QKV, AO, BT, shift);
    mgemm_k<2, 0, 0><<<dim3(392, 1), 256, 0, stream>>>(
        AO, proj_w + (long)layer * 128 * 128, proj_b + layer * 128, X, 128, 128, 128, shift);
    ln_k<<<NTOK / 4, 256, 0, stream>>>(X, XN, norm2_g + layer * 128, norm2_b + layer * 128, 0);
    mgemm_k<0, 1, 0><<<dim3(392, 4), 256, 0, stream>>>(
        XN, fc1_w + (long)layer * 128 * 512, fc1_b + layer * 512, Hb, 512, 128, 128, 0);
    mgemm_k<3, 0, 0><<<dim3(392, 1), 256, 0, stream>>>(
        Hb, fc2_w + (long)layer * 512 * 128, fc2_b + layer * 128, X, 128, 512, 512, 0);
  }

  ln_k<<<NTOK / 4, 256, 0, stream>>>(X, Y, normf_g, normf_b, 1);
  w1split_k<<<32, 256, 0, stream>>>(h1w, BHG, BLG);
  head_mfma_k<<<6272, 256, 0, stream>>>(Y, BHG, BLG, h1b, h2w, h2b, out);
}